// Round 14
// baseline (271.790 us; speedup 1.0000x reference)
//
#include <hip/hip_runtime.h>
#include <hip/hip_bf16.h>
#include <stdint.h>

// MoE top-2 of 8 experts.  B=2,T=1024 -> nt=2048 tokens, D=1024, H=4096, E=8.
// d_out layout: out[2*1024*1024] f32 | gate_value[2048*8] f32 | lb_loss[1] f32.
//
// R14:
//  - gemm2 KSPLIT back to 2 (KSPLIT=4 refuted in R13: doubled atomic
//    epilogue passes, 108us vs 89).
//  - gemm2 tile M 128->64 (64x128, ring-3 LDS 36KB): active blocks
//    512->1024 = 4/CU, matching LDS capacity.  A staged with 1 gld16/step,
//    B with 2; vmcnt(3) counted wait (3 loads/tile in flight).
//  - gemm1 unchanged (R6 core, 458 TF measured, don't touch).
//  - preA = conv_W1 || gate || zero (2048 blocks, one dispatch wave);
//    stats+compact fused; conv_W2 before gemm2; direct-out atomic epilogue.

#define NTOK 2048
#define DDIM 1024
#define HDIM 4096
#define NEXP 8
#define KSPLIT 2
#define CONVB 1024
#define GATEB (NTOK / 4)
#define ZEROB 512

typedef float  f32x4  __attribute__((ext_vector_type(4)));
typedef __bf16 bf16x8 __attribute__((ext_vector_type(8)));
typedef __bf16 bf16x4 __attribute__((ext_vector_type(4)));

typedef const __attribute__((address_space(1))) void g1_t;
typedef __attribute__((address_space(3))) void l3_t;
__device__ __forceinline__ void gld16(const void* g, void* l) {
  __builtin_amdgcn_global_load_lds((g1_t*)g, (l3_t*)l, 16, 0, 0);
}

// ---------------- bodies for the fused pre-pass ----------------
__device__ __forceinline__ void conv_body(int bid, const float* __restrict__ src,
                                          __bf16* __restrict__ dst, long n8) {
  long i = (long)bid * 256 + threadIdx.x;
  long stride = (long)CONVB * 256;
  for (; i < n8; i += stride) {
    f32x4 a = ((const f32x4*)src)[2 * i];
    f32x4 b = ((const f32x4*)src)[2 * i + 1];
    bf16x8 o;
#pragma unroll
    for (int q = 0; q < 4; ++q) { o[q] = (__bf16)a[q]; o[q + 4] = (__bf16)b[q]; }
    ((bf16x8*)dst)[i] = o;
  }
}

__device__ __forceinline__ void zero_body(int bid, float* __restrict__ y, long n4) {
  long i = (long)bid * 256 + threadIdx.x;
  long stride = (long)ZEROB * 256;
  for (; i < n4; i += stride) ((f32x4*)y)[i] = (f32x4){0.f, 0.f, 0.f, 0.f};
}

__device__ __forceinline__ void gate_body(int bid, const float* __restrict__ x,
                                          const unsigned char* __restrict__ pmask,
                                          const float* __restrict__ Wg,
                                          float* __restrict__ gate_out,
                                          int* __restrict__ tix, float* __restrict__ twt,
                                          __bf16* __restrict__ xbf) {
  int wave = threadIdx.x >> 6, lane = threadIdx.x & 63;
  int t = bid * 4 + wave;   // one wave per token
  const f32x4* x4 = (const f32x4*)(x + (size_t)t * DDIM);
  const f32x4* w4 = (const f32x4*)Wg;
  bf16x4* xb4 = (bf16x4*)(xbf + (size_t)t * DDIM);
  float acc[NEXP];
#pragma unroll
  for (int e = 0; e < NEXP; ++e) acc[e] = 0.f;
#pragma unroll
  for (int i = 0; i < 4; ++i) {
    f32x4 xv = x4[i * 64 + lane];
    bf16x4 xo;
#pragma unroll
    for (int q = 0; q < 4; ++q) xo[q] = (__bf16)xv[q];
    xb4[i * 64 + lane] = xo;
#pragma unroll
    for (int e = 0; e < NEXP; ++e) {
      f32x4 wv = w4[e * 256 + i * 64 + lane];
      acc[e] += xv[0]*wv[0] + xv[1]*wv[1] + xv[2]*wv[2] + xv[3]*wv[3];
    }
  }
#pragma unroll
  for (int e = 0; e < NEXP; ++e) {
    float v = acc[e];
#pragma unroll
    for (int off = 32; off > 0; off >>= 1) v += __shfl_xor(v, off, 64);
    acc[e] = v;
  }
  if (lane == 0) {
    bool pm = pmask[t] != 0;
    float m = acc[0];
#pragma unroll
    for (int e = 1; e < NEXP; ++e) m = fmaxf(m, acc[e]);
    float g[NEXP]; float s = 0.f;
#pragma unroll
    for (int e = 0; e < NEXP; ++e) { g[e] = expf(acc[e] - m); s += g[e]; }
    float inv = 1.f / s;
#pragma unroll
    for (int e = 0; e < NEXP; ++e) g[e] *= inv;
    if (pm) {
#pragma unroll
      for (int e = 0; e < NEXP; ++e) g[e] = 0.f;
    }
    int i1 = 0;
#pragma unroll
    for (int e = 1; e < NEXP; ++e) if (g[e] > g[i1]) i1 = e;
    int i2 = -1;
#pragma unroll
    for (int e = 0; e < NEXP; ++e) if (e != i1 && (i2 < 0 || g[e] > g[i2])) i2 = e;
    float w1 = g[i1], w2 = g[i2], ss = w1 + w2;
    if (ss == 0.f) ss = 1.f;
    w1 /= ss; w2 /= ss;
#pragma unroll
    for (int e = 0; e < NEXP; ++e) gate_out[(size_t)t * NEXP + e] = g[e];
    tix[2*t] = i1; tix[2*t+1] = i2;
    twt[2*t] = w1; twt[2*t+1] = w2;
  }
}

// ---------------- preA: conv_W1 || gate || zero_out (2048 blocks, one wave) ----------------
__global__ __launch_bounds__(256)
void preA_kernel(const float* __restrict__ x, const unsigned char* __restrict__ pmask,
                 const float* __restrict__ Wg, float* __restrict__ gate_out,
                 int* __restrict__ tix, float* __restrict__ twt,
                 __bf16* __restrict__ xbf, const float* __restrict__ W1,
                 __bf16* __restrict__ w1bf, float* __restrict__ out)
{
  int bid = blockIdx.x;
  if (bid < CONVB) { conv_body(bid, W1, w1bf, (long)NEXP * HDIM * DDIM / 8); return; }
  bid -= CONVB;
  if (bid < GATEB) { gate_body(bid, x, pmask, Wg, gate_out, tix, twt, xbf); return; }
  bid -= GATEB;
  zero_body(bid, out, (long)NTOK * DDIM / 4);
}

__global__ __launch_bounds__(256)
void conv_kernel(const float* __restrict__ src, __bf16* __restrict__ dst, long n8)
{
  conv_body(blockIdx.x, src, dst, n8);
}

// ---------------- stats+compact: single block -> ecount/offs/lb + token lists ----------------
__global__ __launch_bounds__(1024)
void stats_kernel(const float* __restrict__ gate_out, const int* __restrict__ tix,
                  const float* __restrict__ twt, const unsigned char* __restrict__ pmask,
                  int* __restrict__ ecount, int* __restrict__ offs_g,
                  float* __restrict__ lb_out, int* __restrict__ tok_list,
                  float* __restrict__ wgt_list)
{
  int tid = threadIdx.x, lane = tid & 63, wv = tid >> 6;   // 16 waves
  float lg[NEXP]; float lt1[NEXP]; int lec[NEXP]; float ln = 0.f;
#pragma unroll
  for (int e = 0; e < NEXP; ++e) { lg[e] = 0.f; lt1[e] = 0.f; lec[e] = 0; }
#pragma unroll
  for (int it = 0; it < NTOK / 1024; ++it) {
    int t = tid + it * 1024;
    f32x4 g0 = ((const f32x4*)(gate_out + (size_t)t * NEXP))[0];
    f32x4 g1 = ((const f32x4*)(gate_out + (size_t)t * NEXP))[1];
    lg[0] += g0[0]; lg[1] += g0[1]; lg[2] += g0[2]; lg[3] += g0[3];
    lg[4] += g1[0]; lg[5] += g1[1]; lg[6] += g1[2]; lg[7] += g1[3];
    if (!pmask[t]) {
      int i1 = tix[2*t], i2 = tix[2*t+1];
      lt1[i1] += 1.f; lec[i1] += 1; lec[i2] += 1; ln += 1.f;
    }
  }
#pragma unroll
  for (int e = 0; e < NEXP; ++e) {
#pragma unroll
    for (int off = 32; off > 0; off >>= 1) {
      lg[e]  += __shfl_xor(lg[e],  off, 64);
      lt1[e] += __shfl_xor(lt1[e], off, 64);
      lec[e] += __shfl_xor(lec[e], off, 64);
    }
  }
#pragma unroll
  for (int off = 32; off > 0; off >>= 1) ln += __shfl_xor(ln, off, 64);
  __shared__ float sg[16][NEXP], st[16][NEXP], sn[16];
  __shared__ int   se[16][NEXP];
  __shared__ int   soffs[NEXP], sfill[NEXP];
  if (lane == 0) {
#pragma unroll
    for (int e = 0; e < NEXP; ++e) { sg[wv][e] = lg[e]; st[wv][e] = lt1[e]; se[wv][e] = lec[e]; }
    sn[wv] = ln;
  }
  __syncthreads();
  if (tid == 0) {
    float G[NEXP] = {0}, T1[NEXP] = {0}; int EC[NEXP] = {0}; float N = 0.f;
    for (int w = 0; w < 16; ++w) {
      N += sn[w];
#pragma unroll
      for (int e = 0; e < NEXP; ++e) { G[e] += sg[w][e]; T1[e] += st[w][e]; EC[e] += se[w][e]; }
    }
    int o = 0;
    for (int e = 0; e < NEXP; ++e) {
      ecount[e] = EC[e]; offs_g[e] = o; soffs[e] = o; sfill[e] = 0; o += EC[e];
    }
    if (N <= 0.f) N = 1.f;
    float lb = 0.f;
    for (int e = 0; e < NEXP; ++e) lb += (T1[e] / N) * (G[e] / N);
    lb_out[0] = (float)NEXP * lb;
  }
  __syncthreads();
  // compaction: ballot-aggregated, LDS fill counters
#pragma unroll
  for (int it = 0; it < NTOK / 1024; ++it) {
    int t = tid + it * 1024;
    bool pm = pmask[t] != 0;
#pragma unroll
    for (int j = 0; j < 2; ++j) {
      int e = pm ? -1 : tix[2*t + j];
#pragma unroll
      for (int ex = 0; ex < NEXP; ++ex) {
        unsigned long long mask = __ballot(e == ex);
        if (mask) {
          int leader = (int)(__ffsll((long long)mask) - 1);
          int base = 0;
          if (lane == leader) base = atomicAdd(&sfill[ex], (int)__popcll(mask));
          base = __shfl(base, leader, 64);
          if (e == ex) {
            int pos = soffs[ex] + base + (int)__popcll(mask & ((1ull << lane) - 1ull));
            tok_list[pos] = t;
            wgt_list[pos] = twt[2*t + j];
          }
        }
      }
    }
  }
}

// ======================= GEMM cores =======================
// Common: ring-3 LDS, 2-deep prefetch, counted vmcnt, raw s_barrier,
// XOR swizzle (LDS chunk cs of row r holds data chunk cd = cs^((r>>1)&3);
// linear gld16 dest, swizzle on global src, undone on fragment read via cg).

// ---------------- GEMM1 (128x128, R6-proven): h = relu(x·W1^T + b1) ----------------
__global__ __launch_bounds__(256)
void gemm1_kernel(const __bf16* __restrict__ xbf, const __bf16* __restrict__ w1bf,
                  const float* __restrict__ b1, const int* __restrict__ ecount,
                  const int* __restrict__ offs, const int* __restrict__ tok_list,
                  __bf16* __restrict__ hbuf)
{
  const int NTILE = HDIM / 128;   // 32
  const int MTILE = NTOK / 128;   // 16
  int bid = blockIdx.x;
  int e = bid / (MTILE * NTILE);
  int rem = bid % (MTILE * NTILE);
  int mt = rem / NTILE, nt = rem % NTILE;
  int cnt = ecount[e];
  if (mt * 128 >= cnt) return;
  int off = offs[e];

  __shared__ __bf16 As[3][128 * 32];
  __shared__ __bf16 Bs[3][128 * 32];

  int tid = threadIdx.x, lane = tid & 63, wave = tid >> 6;
  int wm = wave >> 1, wn = wave & 1;

  const __bf16* aP[2];
  const __bf16* bP[2];
#pragma unroll
  for (int c = 0; c < 2; ++c) {
    int row = c * 64 + (tid >> 2);
    int cd = (tid & 3) ^ ((row >> 1) & 3);
    int mrow = mt * 128 + row;
    int tok = tok_list[off + ((mrow < cnt) ? mrow : 0)];
    aP[c] = xbf + (size_t)tok * DDIM + cd * 8;
    bP[c] = w1bf + (size_t)e * HDIM * DDIM + (size_t)(nt * 128 + row) * DDIM + cd * 8;
  }
  int cg = ((lane >> 4) ^ ((lane >> 1) & 3)) << 3;

  f32x4 acc[4][4];
#pragma unroll
  for (int m = 0; m < 4; ++m)
#pragma unroll
    for (int n = 0; n < 4; ++n) acc[m][n] = (f32x4){0.f, 0.f, 0.f, 0.f};

  const int NIT = DDIM / 32;   // 32
#pragma unroll
  for (int pt = 0; pt < 2; ++pt)
#pragma unroll
    for (int c = 0; c < 2; ++c) {
      gld16(aP[c] + pt * 32, &As[pt][(c * 64 + wave * 16) * 32]);
      gld16(bP[c] + pt * 32, &Bs[pt][(c * 64 + wave * 16) * 32]);
    }

  for (int it = 0; it < NIT; ++it) {
    int cur = it % 3;
    if (it + 1 < NIT) asm volatile("s_waitcnt vmcnt(4)" ::: "memory");
    else              asm volatile("s_waitcnt vmcnt(0)" ::: "memory");
    __builtin_amdgcn_s_barrier();
    __builtin_amdgcn_sched_barrier(0);
    if (it + 2 < NIT) {
      int nb = (it + 2) % 3;
      int k0 = (it + 2) * 32;
#pragma unroll
      for (int c = 0; c < 2; ++c) {
        gld16(aP[c] + k0, &As[nb][(c * 64 + wave * 16) * 32]);
        gld16(bP[c] + k0, &Bs[nb][(c * 64 + wave * 16) * 32]);
      }
    }
    bf16x8 af[4], bfr[4];
#pragma unroll
    for (int m = 0; m < 4; ++m) af[m]  = *(const bf16x8*)&As[cur][(wm*64 + m*16 + (lane & 15)) * 32 + cg];
#pragma unroll
    for (int n = 0; n < 4; ++n) bfr[n] = *(const bf16x8*)&Bs[cur][(wn*64 + n*16 + (lane & 15)) * 32 + cg];
#pragma unroll
    for (int m = 0; m < 4; ++m)
#pragma unroll
      for (int n = 0; n < 4; ++n)
        acc[m][n] = __builtin_amdgcn_mfma_f32_16x16x32_bf16(af[m], bfr[n], acc[m][n], 0, 0, 0);
  }

  // epilogue: +bias, relu, bf16 store
#pragma unroll
  for (int n = 0; n < 4; ++n) {
    int col = nt * 128 + wn * 64 + n * 16 + (lane & 15);
    float bias = b1[e * HDIM + col];
#pragma unroll
    for (int m = 0; m < 4; ++m) {
#pragma unroll
      for (int j = 0; j < 4; ++j) {
        int mr = mt * 128 + wm * 64 + m * 16 + ((lane >> 4) << 2) + j;
        if (mr < cnt) {
          float v = fmaxf(acc[m][n][j] + bias, 0.f);
          hbuf[(size_t)(off + mr) * HDIM + col] = (__bf16)v;
        }
      }
    }
  }
}

// ---------------- GEMM2 (64x128, KSPLIT=2): out[tok,:] += w*(h·W2^T + b2) ----------------
// M=64 tile: blocks = 8e x 8mt x 8nt x 2 = 1024 = 4/CU; ring-3 LDS 36KB
// fits 4 blocks/CU.  3 loads/thread/tile (1 A + 2 B) -> vmcnt(3).
// Waves 2x2: per-wave 32m x 64n = 2x4 frags.
__global__ __launch_bounds__(256)
void gemm2_kernel(const __bf16* __restrict__ hbuf, const __bf16* __restrict__ w2bf,
                  const float* __restrict__ b2, const int* __restrict__ ecount,
                  const int* __restrict__ offs, const int* __restrict__ tok_list,
                  const float* __restrict__ wgt_list, float* __restrict__ out)
{
  const int NTILE = DDIM / 128;   // 8
  const int MTILE = NTOK / 64;    // 32
  int bid = blockIdx.x;
  int e = bid / (MTILE * NTILE * KSPLIT);
  int rem = bid % (MTILE * NTILE * KSPLIT);
  int mt = rem / (NTILE * KSPLIT);
  int rem2 = rem % (NTILE * KSPLIT);
  int nt = rem2 / KSPLIT, kc = rem2 % KSPLIT;
  int cnt = ecount[e];
  if (mt * 64 >= cnt) return;
  int off = offs[e];

  __shared__ __bf16 As[3][64 * 32];
  __shared__ __bf16 Bs[3][128 * 32];

  int tid = threadIdx.x, lane = tid & 63, wave = tid >> 6;
  int wm = wave >> 1, wn = wave & 1;

  // A (hbuf): 1 gld16 per K-step; thread stages row tid>>2 (64 rows), chunk tid&3
  const __bf16* aP;
  {
    int row = tid >> 2;
    int cd = (tid & 3) ^ ((row >> 1) & 3);
    aP = hbuf + (size_t)(off + mt * 64 + row) * HDIM + cd * 8;
  }
  // B (W2): 2 gld16 per K-step
  const __bf16* bP[2];
#pragma unroll
  for (int c = 0; c < 2; ++c) {
    int row = c * 64 + (tid >> 2);
    int cd = (tid & 3) ^ ((row >> 1) & 3);
    bP[c] = w2bf + (size_t)e * DDIM * HDIM + (size_t)(nt * 128 + row) * HDIM + cd * 8;
  }
  int cg = ((lane >> 4) ^ ((lane >> 1) & 3)) << 3;

  f32x4 acc[2][4];
#pragma unroll
  for (int m = 0; m < 2; ++m)
#pragma unroll
    for (int n = 0; n < 4; ++n) acc[m][n] = (f32x4){0.f, 0.f, 0.f, 0.f};

  const int KCH = HDIM / KSPLIT;      // 2048
  const int NIT = KCH / 32;           // 64
  int kbeg = kc * KCH;
#pragma unroll
  for (int pt = 0; pt < 2; ++pt) {
    gld16(aP + kbeg + pt * 32, &As[pt][(wave * 16) * 32]);
#pragma unroll
    for (int c = 0; c < 2; ++c)
      gld16(bP[c] + kbeg + pt * 32, &Bs[pt][(c * 64 + wave * 16) * 32]);
  }

  for (int it = 0; it < NIT; ++it) {
    int cur = it % 3;
    if (it + 1 < NIT) asm volatile("s_waitcnt vmcnt(3)" ::: "memory");
    else              asm volatile("s_waitcnt vmcnt(0)" ::: "memory");
    __builtin_amdgcn_s_barrier();
    __builtin_amdgcn_sched_barrier(0);
    if (it + 2 < NIT) {
      int nb = (it + 2) % 3;
      int k0 = kbeg + (it + 2) * 32;
      gld16(aP + k0, &As[nb][(wave * 16) * 32]);
#pragma unroll
      for (int c = 0; c < 2; ++c)
        gld16(bP[c] + k0, &Bs[nb][(c * 64 + wave * 16) * 32]);
    }
    bf16x8 af[2], bfr[4];
#pragma unroll
    for (int m = 0; m < 2; ++m) af[m]  = *(const bf16x8*)&As[cur][(wm*32 + m*16 + (lane & 15)) * 32 + cg];
#pragma unroll
    for (int n = 0; n < 4; ++n) bfr[n] = *(const bf16x8*)&Bs[cur][(wn*64 + n*16 + (lane & 15)) * 32 + cg];
#pragma unroll
    for (int m = 0; m < 2; ++m)
#pragma unroll
      for (int n = 0; n < 4; ++n)
        acc[m][n] = __builtin_amdgcn_mfma_f32_16x16x32_bf16(af[m], bfr[n], acc[m][n], 0, 0, 0);
  }

  // epilogue: atomic accumulate w*(acc [+ b2 on kc==0]) directly into out
  float b2v[4];
#pragma unroll
  for (int n = 0; n < 4; ++n) {
    int col = nt * 128 + wn * 64 + n * 16 + (lane & 15);
    b2v[n] = (kc == 0) ? b2[e * DDIM + col] : 0.f;
  }
#pragma unroll
  for (int m = 0; m < 2; ++m) {
#pragma unroll
    for (int j = 0; j < 4; ++j) {
      int mr = mt * 64 + wm * 32 + m * 16 + ((lane >> 4) << 2) + j;
      if (mr >= cnt) continue;
      int slot = off + mr;
      int tok = tok_list[slot];
      float w = wgt_list[slot];
      float* obase = out + (size_t)tok * DDIM;
#pragma unroll
      for (int n = 0; n < 4; ++n) {
        int col = nt * 128 + wn * 64 + n * 16 + (lane & 15);
        atomicAdd(obase + col, w * (acc[m][n][j] + b2v[n]));
      }
    }
  }
}

extern "C" void kernel_launch(void* const* d_in, const int* in_sizes, int n_in,
                              void* d_out, int out_size, void* d_ws, size_t ws_size,
                              hipStream_t stream)
{
  const float* x  = (const float*)d_in[0];
  const unsigned char* pm = (const unsigned char*)d_in[1];
  const float* Wg = (const float*)d_in[2];
  const float* W1 = (const float*)d_in[3];
  const float* b1 = (const float*)d_in[4];
  const float* W2 = (const float*)d_in[5];
  const float* b2 = (const float*)d_in[6];
  float* out = (float*)d_out;
  float* gate_out = out + (size_t)NTOK * DDIM;        // 2097152
  float* lb_out = gate_out + (size_t)NTOK * NEXP;     // 2113536

  char* w = (char*)d_ws;
  int*   ecount   = (int*)(w + 0);
  int*   offs     = (int*)(w + 64);
  int*   tix      = (int*)(w + 512);                       // 16 KB
  float* twt      = (float*)(w + 512 + 16384);             // 16 KB
  int*   tok_list = (int*)(w + 512 + 32768);               // 16 KB
  float* wgt_list = (float*)(w + 512 + 49152);             // 16 KB
  uintptr_t p = ((uintptr_t)(w + 512 + 65536) + 255) & ~(uintptr_t)255;
  __bf16* xbf  = (__bf16*)p;                                    // 4 MB
  p += (size_t)NTOK * DDIM * 2;
  __bf16* w1bf = (__bf16*)p;                                    // 64 MB
  p += (size_t)NEXP * HDIM * DDIM * 2;
  __bf16* hbuf = (__bf16*)p;                                    // 33 MB
  p += (size_t)(2 * NTOK + 128) * HDIM * 2;
  __bf16* w2bf_sep = (__bf16*)p;                                // 64 MB if it fits
  size_t need = (size_t)((char*)(w2bf_sep + (size_t)NEXP * DDIM * HDIM) - w);
  __bf16* w2bf = (ws_size >= need) ? w2bf_sep : w1bf;  // alias safe: conv_W2 runs after gemm1

  preA_kernel<<<CONVB + GATEB + ZEROB, 256, 0, stream>>>(
      x, pm, Wg, gate_out, tix, twt, xbf, W1, w1bf, out);
  stats_kernel<<<1, 1024, 0, stream>>>(gate_out, tix, twt, pm, ecount, offs, lb_out,
                                       tok_list, wgt_list);
  gemm1_kernel<<<NEXP * (NTOK / 128) * (HDIM / 128), 256, 0, stream>>>(
      xbf, w1bf, b1, ecount, offs, tok_list, hbuf);
  conv_kernel<<<CONVB, 256, 0, stream>>>(W2, w2bf, (long)NEXP * DDIM * HDIM / 8);
  gemm2_kernel<<<NEXP * (NTOK / 64) * (DDIM / 128) * KSPLIT, 256, 0, stream>>>(
      hbuf, w2bf, b2, ecount, offs, tok_list, wgt_list, out);
}

// Round 15
// 245.790 us; speedup vs baseline: 1.1058x; 1.1058x over previous
//
#include <hip/hip_runtime.h>
#include <hip/hip_bf16.h>
#include <stdint.h>

// MoE top-2 of 8 experts.  B=2,T=1024 -> nt=2048 tokens, D=1024, H=4096, E=8.
// d_out layout: out[2*1024*1024] f32 | gate_value[2048*8] f32 | lb_loss[1] f32.
//
// R15 = best-measured assembly (R11 config, 249.5us) + R13's neutral
// dispatch fusion:
//  - preA = conv_W1 || gate || zero_out, 2048 blocks = one dispatch wave.
//  - stats+compact fused single-block.
//  - gemm1: 128x128, BK=32, ring-3 LDS, counted vmcnt(4), raw s_barrier,
//    XOR swizzle (75us, 458 TF measured).
//  - conv_W2 separate 1024-block dispatch.
//  - gemm2: 128x128, KSPLIT=2, direct-out atomic epilogue (89us measured).
// Design space mapped & refuted: wide tiles (R10), KSPLIT=4 (R13),
// M=64 (R14), f32-direct B (R7/R8), grid-union conv||GEMM (R9/R12),
// deeper HIP-source pipelining (R5/R6 marginal).

#define NTOK 2048
#define DDIM 1024
#define HDIM 4096
#define NEXP 8
#define KSPLIT 2
#define CONVB 1024
#define GATEB (NTOK / 4)
#define ZEROB 512

typedef float  f32x4  __attribute__((ext_vector_type(4)));
typedef __bf16 bf16x8 __attribute__((ext_vector_type(8)));
typedef __bf16 bf16x4 __attribute__((ext_vector_type(4)));

typedef const __attribute__((address_space(1))) void g1_t;
typedef __attribute__((address_space(3))) void l3_t;
__device__ __forceinline__ void gld16(const void* g, void* l) {
  __builtin_amdgcn_global_load_lds((g1_t*)g, (l3_t*)l, 16, 0, 0);
}

// ---------------- bodies for the fused pre-pass ----------------
__device__ __forceinline__ void conv_body(int bid, const float* __restrict__ src,
                                          __bf16* __restrict__ dst, long n8) {
  long i = (long)bid * 256 + threadIdx.x;
  long stride = (long)CONVB * 256;
  for (; i < n8; i += stride) {
    f32x4 a = ((const f32x4*)src)[2 * i];
    f32x4 b = ((const f32x4*)src)[2 * i + 1];
    bf16x8 o;
#pragma unroll
    for (int q = 0; q < 4; ++q) { o[q] = (__bf16)a[q]; o[q + 4] = (__bf16)b[q]; }
    ((bf16x8*)dst)[i] = o;
  }
}

__device__ __forceinline__ void zero_body(int bid, float* __restrict__ y, long n4) {
  long i = (long)bid * 256 + threadIdx.x;
  long stride = (long)ZEROB * 256;
  for (; i < n4; i += stride) ((f32x4*)y)[i] = (f32x4){0.f, 0.f, 0.f, 0.f};
}

__device__ __forceinline__ void gate_body(int bid, const float* __restrict__ x,
                                          const unsigned char* __restrict__ pmask,
                                          const float* __restrict__ Wg,
                                          float* __restrict__ gate_out,
                                          int* __restrict__ tix, float* __restrict__ twt,
                                          __bf16* __restrict__ xbf) {
  int wave = threadIdx.x >> 6, lane = threadIdx.x & 63;
  int t = bid * 4 + wave;   // one wave per token
  const f32x4* x4 = (const f32x4*)(x + (size_t)t * DDIM);
  const f32x4* w4 = (const f32x4*)Wg;
  bf16x4* xb4 = (bf16x4*)(xbf + (size_t)t * DDIM);
  float acc[NEXP];
#pragma unroll
  for (int e = 0; e < NEXP; ++e) acc[e] = 0.f;
#pragma unroll
  for (int i = 0; i < 4; ++i) {
    f32x4 xv = x4[i * 64 + lane];
    bf16x4 xo;
#pragma unroll
    for (int q = 0; q < 4; ++q) xo[q] = (__bf16)xv[q];
    xb4[i * 64 + lane] = xo;
#pragma unroll
    for (int e = 0; e < NEXP; ++e) {
      f32x4 wv = w4[e * 256 + i * 64 + lane];
      acc[e] += xv[0]*wv[0] + xv[1]*wv[1] + xv[2]*wv[2] + xv[3]*wv[3];
    }
  }
#pragma unroll
  for (int e = 0; e < NEXP; ++e) {
    float v = acc[e];
#pragma unroll
    for (int off = 32; off > 0; off >>= 1) v += __shfl_xor(v, off, 64);
    acc[e] = v;
  }
  if (lane == 0) {
    bool pm = pmask[t] != 0;
    float m = acc[0];
#pragma unroll
    for (int e = 1; e < NEXP; ++e) m = fmaxf(m, acc[e]);
    float g[NEXP]; float s = 0.f;
#pragma unroll
    for (int e = 0; e < NEXP; ++e) { g[e] = expf(acc[e] - m); s += g[e]; }
    float inv = 1.f / s;
#pragma unroll
    for (int e = 0; e < NEXP; ++e) g[e] *= inv;
    if (pm) {
#pragma unroll
      for (int e = 0; e < NEXP; ++e) g[e] = 0.f;
    }
    int i1 = 0;
#pragma unroll
    for (int e = 1; e < NEXP; ++e) if (g[e] > g[i1]) i1 = e;
    int i2 = -1;
#pragma unroll
    for (int e = 0; e < NEXP; ++e) if (e != i1 && (i2 < 0 || g[e] > g[i2])) i2 = e;
    float w1 = g[i1], w2 = g[i2], ss = w1 + w2;
    if (ss == 0.f) ss = 1.f;
    w1 /= ss; w2 /= ss;
#pragma unroll
    for (int e = 0; e < NEXP; ++e) gate_out[(size_t)t * NEXP + e] = g[e];
    tix[2*t] = i1; tix[2*t+1] = i2;
    twt[2*t] = w1; twt[2*t+1] = w2;
  }
}

// ---------------- preA: conv_W1 || gate || zero_out (2048 blocks, one wave) ----------------
__global__ __launch_bounds__(256)
void preA_kernel(const float* __restrict__ x, const unsigned char* __restrict__ pmask,
                 const float* __restrict__ Wg, float* __restrict__ gate_out,
                 int* __restrict__ tix, float* __restrict__ twt,
                 __bf16* __restrict__ xbf, const float* __restrict__ W1,
                 __bf16* __restrict__ w1bf, float* __restrict__ out)
{
  int bid = blockIdx.x;
  if (bid < CONVB) { conv_body(bid, W1, w1bf, (long)NEXP * HDIM * DDIM / 8); return; }
  bid -= CONVB;
  if (bid < GATEB) { gate_body(bid, x, pmask, Wg, gate_out, tix, twt, xbf); return; }
  bid -= GATEB;
  zero_body(bid, out, (long)NTOK * DDIM / 4);
}

__global__ __launch_bounds__(256)
void conv_kernel(const float* __restrict__ src, __bf16* __restrict__ dst, long n8)
{
  conv_body(blockIdx.x, src, dst, n8);
}

// ---------------- stats+compact: single block -> ecount/offs/lb + token lists ----------------
__global__ __launch_bounds__(1024)
void stats_kernel(const float* __restrict__ gate_out, const int* __restrict__ tix,
                  const float* __restrict__ twt, const unsigned char* __restrict__ pmask,
                  int* __restrict__ ecount, int* __restrict__ offs_g,
                  float* __restrict__ lb_out, int* __restrict__ tok_list,
                  float* __restrict__ wgt_list)
{
  int tid = threadIdx.x, lane = tid & 63, wv = tid >> 6;   // 16 waves
  float lg[NEXP]; float lt1[NEXP]; int lec[NEXP]; float ln = 0.f;
#pragma unroll
  for (int e = 0; e < NEXP; ++e) { lg[e] = 0.f; lt1[e] = 0.f; lec[e] = 0; }
#pragma unroll
  for (int it = 0; it < NTOK / 1024; ++it) {
    int t = tid + it * 1024;
    f32x4 g0 = ((const f32x4*)(gate_out + (size_t)t * NEXP))[0];
    f32x4 g1 = ((const f32x4*)(gate_out + (size_t)t * NEXP))[1];
    lg[0] += g0[0]; lg[1] += g0[1]; lg[2] += g0[2]; lg[3] += g0[3];
    lg[4] += g1[0]; lg[5] += g1[1]; lg[6] += g1[2]; lg[7] += g1[3];
    if (!pmask[t]) {
      int i1 = tix[2*t], i2 = tix[2*t+1];
      lt1[i1] += 1.f; lec[i1] += 1; lec[i2] += 1; ln += 1.f;
    }
  }
#pragma unroll
  for (int e = 0; e < NEXP; ++e) {
#pragma unroll
    for (int off = 32; off > 0; off >>= 1) {
      lg[e]  += __shfl_xor(lg[e],  off, 64);
      lt1[e] += __shfl_xor(lt1[e], off, 64);
      lec[e] += __shfl_xor(lec[e], off, 64);
    }
  }
#pragma unroll
  for (int off = 32; off > 0; off >>= 1) ln += __shfl_xor(ln, off, 64);
  __shared__ float sg[16][NEXP], st[16][NEXP], sn[16];
  __shared__ int   se[16][NEXP];
  __shared__ int   soffs[NEXP], sfill[NEXP];
  if (lane == 0) {
#pragma unroll
    for (int e = 0; e < NEXP; ++e) { sg[wv][e] = lg[e]; st[wv][e] = lt1[e]; se[wv][e] = lec[e]; }
    sn[wv] = ln;
  }
  __syncthreads();
  if (tid == 0) {
    float G[NEXP] = {0}, T1[NEXP] = {0}; int EC[NEXP] = {0}; float N = 0.f;
    for (int w = 0; w < 16; ++w) {
      N += sn[w];
#pragma unroll
      for (int e = 0; e < NEXP; ++e) { G[e] += sg[w][e]; T1[e] += st[w][e]; EC[e] += se[w][e]; }
    }
    int o = 0;
    for (int e = 0; e < NEXP; ++e) {
      ecount[e] = EC[e]; offs_g[e] = o; soffs[e] = o; sfill[e] = 0; o += EC[e];
    }
    if (N <= 0.f) N = 1.f;
    float lb = 0.f;
    for (int e = 0; e < NEXP; ++e) lb += (T1[e] / N) * (G[e] / N);
    lb_out[0] = (float)NEXP * lb;
  }
  __syncthreads();
  // compaction: ballot-aggregated, LDS fill counters
#pragma unroll
  for (int it = 0; it < NTOK / 1024; ++it) {
    int t = tid + it * 1024;
    bool pm = pmask[t] != 0;
#pragma unroll
    for (int j = 0; j < 2; ++j) {
      int e = pm ? -1 : tix[2*t + j];
#pragma unroll
      for (int ex = 0; ex < NEXP; ++ex) {
        unsigned long long mask = __ballot(e == ex);
        if (mask) {
          int leader = (int)(__ffsll((long long)mask) - 1);
          int base = 0;
          if (lane == leader) base = atomicAdd(&sfill[ex], (int)__popcll(mask));
          base = __shfl(base, leader, 64);
          if (e == ex) {
            int pos = soffs[ex] + base + (int)__popcll(mask & ((1ull << lane) - 1ull));
            tok_list[pos] = t;
            wgt_list[pos] = twt[2*t + j];
          }
        }
      }
    }
  }
}

// ======================= GEMM cores (R6/R11-proven) =======================
// 128x128 tile, BK=32, ring-3 LDS (48KB), 2-deep prefetch, counted
// s_waitcnt vmcnt(4) + raw s_barrier (one per K-step; vmcnt(0) only at
// the tail).  Swizzle: LDS chunk cs of row r holds data chunk
// cd = cs^((r>>1)&3); linear gld16 dest, swizzle on global src address,
// undone on the fragment ds_read (cg).  0 bank conflicts measured.

// ---------------- GEMM1: h[slot,:] = relu(xbf[tok]·W1bf[e]^T + b1[e]) ----------------
__global__ __launch_bounds__(256)
void gemm1_kernel(const __bf16* __restrict__ xbf, const __bf16* __restrict__ w1bf,
                  const float* __restrict__ b1, const int* __restrict__ ecount,
                  const int* __restrict__ offs, const int* __restrict__ tok_list,
                  __bf16* __restrict__ hbuf)
{
  const int NTILE = HDIM / 128;   // 32
  const int MTILE = NTOK / 128;   // 16
  int bid = blockIdx.x;
  int e = bid / (MTILE * NTILE);
  int rem = bid % (MTILE * NTILE);
  int mt = rem / NTILE, nt = rem % NTILE;
  int cnt = ecount[e];
  if (mt * 128 >= cnt) return;
  int off = offs[e];

  __shared__ __bf16 As[3][128 * 32];
  __shared__ __bf16 Bs[3][128 * 32];

  int tid = threadIdx.x, lane = tid & 63, wave = tid >> 6;
  int wm = wave >> 1, wn = wave & 1;

  const __bf16* aP[2];
  const __bf16* bP[2];
#pragma unroll
  for (int c = 0; c < 2; ++c) {
    int row = c * 64 + (tid >> 2);
    int cd = (tid & 3) ^ ((row >> 1) & 3);
    int mrow = mt * 128 + row;
    int tok = tok_list[off + ((mrow < cnt) ? mrow : 0)];
    aP[c] = xbf + (size_t)tok * DDIM + cd * 8;
    bP[c] = w1bf + (size_t)e * HDIM * DDIM + (size_t)(nt * 128 + row) * DDIM + cd * 8;
  }
  int cg = ((lane >> 4) ^ ((lane >> 1) & 3)) << 3;

  f32x4 acc[4][4];
#pragma unroll
  for (int m = 0; m < 4; ++m)
#pragma unroll
    for (int n = 0; n < 4; ++n) acc[m][n] = (f32x4){0.f, 0.f, 0.f, 0.f};

  const int NIT = DDIM / 32;   // 32
#pragma unroll
  for (int pt = 0; pt < 2; ++pt)
#pragma unroll
    for (int c = 0; c < 2; ++c) {
      gld16(aP[c] + pt * 32, &As[pt][(c * 64 + wave * 16) * 32]);
      gld16(bP[c] + pt * 32, &Bs[pt][(c * 64 + wave * 16) * 32]);
    }

  for (int it = 0; it < NIT; ++it) {
    int cur = it % 3;
    if (it + 1 < NIT) asm volatile("s_waitcnt vmcnt(4)" ::: "memory");
    else              asm volatile("s_waitcnt vmcnt(0)" ::: "memory");
    __builtin_amdgcn_s_barrier();
    __builtin_amdgcn_sched_barrier(0);
    if (it + 2 < NIT) {
      int nb = (it + 2) % 3;
      int k0 = (it + 2) * 32;
#pragma unroll
      for (int c = 0; c < 2; ++c) {
        gld16(aP[c] + k0, &As[nb][(c * 64 + wave * 16) * 32]);
        gld16(bP[c] + k0, &Bs[nb][(c * 64 + wave * 16) * 32]);
      }
    }
    bf16x8 af[4], bfr[4];
#pragma unroll
    for (int m = 0; m < 4; ++m) af[m]  = *(const bf16x8*)&As[cur][(wm*64 + m*16 + (lane & 15)) * 32 + cg];
#pragma unroll
    for (int n = 0; n < 4; ++n) bfr[n] = *(const bf16x8*)&Bs[cur][(wn*64 + n*16 + (lane & 15)) * 32 + cg];
#pragma unroll
    for (int m = 0; m < 4; ++m)
#pragma unroll
      for (int n = 0; n < 4; ++n)
        acc[m][n] = __builtin_amdgcn_mfma_f32_16x16x32_bf16(af[m], bfr[n], acc[m][n], 0, 0, 0);
  }

  // epilogue: +bias, relu, bf16 store
#pragma unroll
  for (int n = 0; n < 4; ++n) {
    int col = nt * 128 + wn * 64 + n * 16 + (lane & 15);
    float bias = b1[e * HDIM + col];
#pragma unroll
    for (int m = 0; m < 4; ++m) {
#pragma unroll
      for (int j = 0; j < 4; ++j) {
        int mr = mt * 128 + wm * 64 + m * 16 + ((lane >> 4) << 2) + j;
        if (mr < cnt) {
          float v = fmaxf(acc[m][n][j] + bias, 0.f);
          hbuf[(size_t)(off + mr) * HDIM + col] = (__bf16)v;
        }
      }
    }
  }
}

// ---------------- GEMM2 (128x128, K-split 2): out[tok,:] += w*(h·W2^T + b2) ----------------
__global__ __launch_bounds__(256)
void gemm2_kernel(const __bf16* __restrict__ hbuf, const __bf16* __restrict__ w2bf,
                  const float* __restrict__ b2, const int* __restrict__ ecount,
                  const int* __restrict__ offs, const int* __restrict__ tok_list,
                  const float* __restrict__ wgt_list, float* __restrict__ out)
{
  const int NTILE = DDIM / 128;   // 8
  const int MTILE = NTOK / 128;   // 16
  int bid = blockIdx.x;
  int e = bid / (MTILE * NTILE * KSPLIT);
  int rem = bid % (MTILE * NTILE * KSPLIT);
  int mt = rem / (NTILE * KSPLIT);
  int rem2 = rem % (NTILE * KSPLIT);
  int nt = rem2 / KSPLIT, kc = rem2 % KSPLIT;
  int cnt = ecount[e];
  if (mt * 128 >= cnt) return;
  int off = offs[e];

  __shared__ __bf16 As[3][128 * 32];
  __shared__ __bf16 Bs[3][128 * 32];

  int tid = threadIdx.x, lane = tid & 63, wave = tid >> 6;
  int wm = wave >> 1, wn = wave & 1;

  const __bf16* aP[2];
  const __bf16* bP[2];
#pragma unroll
  for (int c = 0; c < 2; ++c) {
    int row = c * 64 + (tid >> 2);
    int cd = (tid & 3) ^ ((row >> 1) & 3);
    aP[c] = hbuf + (size_t)(off + mt * 128 + row) * HDIM + cd * 8;
    bP[c] = w2bf + (size_t)e * DDIM * HDIM + (size_t)(nt * 128 + row) * HDIM + cd * 8;
  }
  int cg = ((lane >> 4) ^ ((lane >> 1) & 3)) << 3;

  f32x4 acc[4][4];
#pragma unroll
  for (int m = 0; m < 4; ++m)
#pragma unroll
    for (int n = 0; n < 4; ++n) acc[m][n] = (f32x4){0.f, 0.f, 0.f, 0.f};

  const int KCH = HDIM / KSPLIT;      // 2048
  const int NIT = KCH / 32;           // 64
  int kbeg = kc * KCH;
#pragma unroll
  for (int pt = 0; pt < 2; ++pt)
#pragma unroll
    for (int c = 0; c < 2; ++c) {
      gld16(aP[c] + kbeg + pt * 32, &As[pt][(c * 64 + wave * 16) * 32]);
      gld16(bP[c] + kbeg + pt * 32, &Bs[pt][(c * 64 + wave * 16) * 32]);
    }

  for (int it = 0; it < NIT; ++it) {
    int cur = it % 3;
    if (it + 1 < NIT) asm volatile("s_waitcnt vmcnt(4)" ::: "memory");
    else              asm volatile("s_waitcnt vmcnt(0)" ::: "memory");
    __builtin_amdgcn_s_barrier();
    __builtin_amdgcn_sched_barrier(0);
    if (it + 2 < NIT) {
      int nb = (it + 2) % 3;
      int k0 = kbeg + (it + 2) * 32;
#pragma unroll
      for (int c = 0; c < 2; ++c) {
        gld16(aP[c] + k0, &As[nb][(c * 64 + wave * 16) * 32]);
        gld16(bP[c] + k0, &Bs[nb][(c * 64 + wave * 16) * 32]);
      }
    }
    bf16x8 af[4], bfr[4];
#pragma unroll
    for (int m = 0; m < 4; ++m) af[m]  = *(const bf16x8*)&As[cur][(wm*64 + m*16 + (lane & 15)) * 32 + cg];
#pragma unroll
    for (int n = 0; n < 4; ++n) bfr[n] = *(const bf16x8*)&Bs[cur][(wn*64 + n*16 + (lane & 15)) * 32 + cg];
#pragma unroll
    for (int m = 0; m < 4; ++m)
#pragma unroll
      for (int n = 0; n < 4; ++n)
        acc[m][n] = __builtin_amdgcn_mfma_f32_16x16x32_bf16(af[m], bfr[n], acc[m][n], 0, 0, 0);
  }

  // epilogue: atomic accumulate w*(acc [+ b2 on kc==0]) directly into out
  float b2v[4];
#pragma unroll
  for (int n = 0; n < 4; ++n) {
    int col = nt * 128 + wn * 64 + n * 16 + (lane & 15);
    b2v[n] = (kc == 0) ? b2[e * DDIM + col] : 0.f;
  }
#pragma unroll
  for (int m = 0; m < 4; ++m) {
#pragma unroll
    for (int j = 0; j < 4; ++j) {
      int mr = mt * 128 + wm * 64 + m * 16 + ((lane >> 4) << 2) + j;
      if (mr >= cnt) continue;
      int slot = off + mr;
      int tok = tok_list[slot];
      float w = wgt_list[slot];
      float* obase = out + (size_t)tok * DDIM;
#pragma unroll
      for (int n = 0; n < 4; ++n) {
        int col = nt * 128 + wn * 64 + n * 16 + (lane & 15);
        atomicAdd(obase + col, w * (acc[m][n][j] + b2v[n]));
      }
    }
  }
}

extern "C" void kernel_launch(void* const* d_in, const int* in_sizes, int n_in,
                              void* d_out, int out_size, void* d_ws, size_t ws_size,
                              hipStream_t stream)
{
  const float* x  = (const float*)d_in[0];
  const unsigned char* pm = (const unsigned char*)d_in[1];
  const float* Wg = (const float*)d_in[2];
  const float* W1 = (const float*)d_in[3];
  const float* b1 = (const float*)d_in[4];
  const float* W2 = (const float*)d_in[5];
  const float* b2 = (const float*)d_in[6];
  float* out = (float*)d_out;
  float* gate_out = out + (size_t)NTOK * DDIM;        // 2097152
  float* lb_out = gate_out + (size_t)NTOK * NEXP;     // 2113536

  char* w = (char*)d_ws;
  int*   ecount   = (int*)(w + 0);
  int*   offs     = (int*)(w + 64);
  int*   tix      = (int*)(w + 512);                       // 16 KB
  float* twt      = (float*)(w + 512 + 16384);             // 16 KB
  int*   tok_list = (int*)(w + 512 + 32768);               // 16 KB
  float* wgt_list = (float*)(w + 512 + 49152);             // 16 KB
  uintptr_t p = ((uintptr_t)(w + 512 + 65536) + 255) & ~(uintptr_t)255;
  __bf16* xbf  = (__bf16*)p;                                    // 4 MB
  p += (size_t)NTOK * DDIM * 2;
  __bf16* w1bf = (__bf16*)p;                                    // 64 MB
  p += (size_t)NEXP * HDIM * DDIM * 2;
  __bf16* hbuf = (__bf16*)p;                                    // 33 MB
  p += (size_t)(2 * NTOK + 128) * HDIM * 2;
  __bf16* w2bf_sep = (__bf16*)p;                                // 64 MB if it fits
  size_t need = (size_t)((char*)(w2bf_sep + (size_t)NEXP * DDIM * HDIM) - w);
  __bf16* w2bf = (ws_size >= need) ? w2bf_sep : w1bf;  // alias safe: conv_W2 runs after gemm1

  preA_kernel<<<CONVB + GATEB + ZEROB, 256, 0, stream>>>(
      x, pm, Wg, gate_out, tix, twt, xbf, W1, w1bf, out);
  stats_kernel<<<1, 1024, 0, stream>>>(gate_out, tix, twt, pm, ecount, offs, lb_out,
                                       tok_list, wgt_list);
  gemm1_kernel<<<NEXP * (NTOK / 128) * (HDIM / 128), 256, 0, stream>>>(
      xbf, w1bf, b1, ecount, offs, tok_list, hbuf);
  conv_kernel<<<CONVB, 256, 0, stream>>>(W2, w2bf, (long)NEXP * DDIM * HDIM / 8);
  gemm2_kernel<<<NEXP * (NTOK / 128) * (DDIM / 128) * KSPLIT, 256, 0, stream>>>(
      hbuf, w2bf, b2, ecount, offs, tok_list, wgt_list, out);
}